// Round 12
// baseline (507.323 us; speedup 1.0000x reference)
//
#include <hip/hip_runtime.h>

#define TILE 32
#define KDIM 320

typedef __attribute__((ext_vector_type(8))) short short8;
typedef __attribute__((ext_vector_type(4))) float f32x4;

__device__ inline unsigned short rne_bf16(float f) {
    union { float f; unsigned u; } x;
    x.f = f;
    unsigned r = (x.u + 0x7FFF + ((x.u >> 16) & 1)) >> 16;
    return (unsigned short)r;
}

__device__ inline float bf16_f(unsigned short v) {
    union { unsigned u; float f; } x;
    x.u = ((unsigned)v) << 16;
    return x.f;
}

// scalar {1.0f, 0.0f} mask in an SGPR (condition is wave-uniform)
#define SMASK(cond) __int_as_float(__builtin_amdgcn_readfirstlane((cond) ? 0x3f800000 : 0))

// ---------------- scans ----------------

__global__ void k_scan1(const int* __restrict__ in, int* __restrict__ out,
                        int* __restrict__ bsum, int M) {
    __shared__ int s[256];
    int t = threadIdx.x;
    int base = blockIdx.x * 1024 + t * 4;
    int v0 = (base + 0 < M) ? in[base + 0] : 0;
    int v1 = (base + 1 < M) ? in[base + 1] : 0;
    int v2 = (base + 2 < M) ? in[base + 2] : 0;
    int v3 = (base + 3 < M) ? in[base + 3] : 0;
    int ts = v0 + v1 + v2 + v3;
    s[t] = ts;
    __syncthreads();
    for (int off = 1; off < 256; off <<= 1) {
        int x = (t >= off) ? s[t - off] : 0;
        __syncthreads();
        s[t] += x;
        __syncthreads();
    }
    int excl = (t == 0) ? 0 : s[t - 1];
    if (t == 255) bsum[blockIdx.x] = s[255];
    if (base + 0 < M) out[base + 0] = excl;
    if (base + 1 < M) out[base + 1] = excl + v0;
    if (base + 2 < M) out[base + 2] = excl + v0 + v1;
    if (base + 3 < M) out[base + 3] = excl + v0 + v1 + v2;
}

__global__ void k_scan2(const int* __restrict__ bsum, int* __restrict__ boff, int nb) {
    __shared__ int s[512];
    int t = threadIdx.x;
    s[t] = (t < nb) ? bsum[t] : 0;
    __syncthreads();
    for (int off = 1; off < 512; off <<= 1) {
        int x = (t >= off) ? s[t - off] : 0;
        __syncthreads();
        s[t] += x;
        __syncthreads();
    }
    if (t < nb) boff[t] = (t == 0) ? 0 : s[t - 1];
}

__global__ void k_scan3(int* __restrict__ out, const int* __restrict__ boff, int M, int E) {
    int i = blockIdx.x * 256 + threadIdx.x;
    if (i < M) out[i] += boff[i >> 10];
    else if (i == M) out[M] = E;
}

__global__ void k_fill(const int* __restrict__ src, const int* __restrict__ dst,
                       const int* __restrict__ typ, const int* __restrict__ start4,
                       const int* __restrict__ rank, int* __restrict__ elist, int E) {
    int e = blockIdx.x * 256 + threadIdx.x;
    if (e < E) {
        int seg = dst[e] * 4 + typ[e];
        elist[start4[seg] + rank[e]] = src[e];
    }
}

// ---------------- fused prep: edge count/rank | x->bf16 | weight pack | graph bounds ----

__global__ void k_prep(const int* __restrict__ dst, const int* __restrict__ typ,
                       int* __restrict__ cnt4, int* __restrict__ rank, int E, int necnt,
                       const float* __restrict__ x, unsigned short* __restrict__ xb, int ncvt,
                       const float* __restrict__ W1, const float* __restrict__ root1,
                       const float* __restrict__ Wl, const float* __restrict__ rootl,
                       unsigned short* __restrict__ Wp, int nwp,
                       const int* __restrict__ batch, int* __restrict__ gstart,
                       int nN, int nG) {
    int b = blockIdx.x;
    if (b < necnt) {
        int e = b * 256 + threadIdx.x;
        if (e < E) {
            int seg = dst[e] * 4 + typ[e];
            rank[e] = atomicAdd(&cnt4[seg], 1);
        }
        return;
    }
    b -= necnt;
    if (b < ncvt) {
        int i = (b * 256 + threadIdx.x) * 4;
        float4 v = *reinterpret_cast<const float4*>(&x[i]);
        ushort4 o;
        o.x = rne_bf16(v.x); o.y = rne_bf16(v.y);
        o.z = rne_bf16(v.z); o.w = rne_bf16(v.w);
        *reinterpret_cast<ushort4*>(&xb[i]) = o;
        return;
    }
    b -= ncvt;
    if (b < nwp) {
        int idx = b * 256 + threadIdx.x;
        const int TOT = 3 * 320 * 64;
        if (idx >= TOT) return;
        int j = idx & 7;
        int lane = (idx >> 3) & 63;
        int t = idx >> 9;
        int ks = t % 10;
        int lnt = t / 10;
        int nt = lnt & 3;
        int layer = lnt >> 2;
        int k = ks * 32 + ((lane >> 4) << 3) + j;
        int h = nt * 16 + (lane & 15);
        float v;
        if (k < 256) {
            v = (layer == 0) ? W1[k * 64 + h] : Wl[(layer - 1) * 16384 + k * 64 + h];
        } else {
            v = (layer == 0) ? root1[(k - 256) * 64 + h]
                             : rootl[(layer - 1) * 4096 + (k - 256) * 64 + h];
        }
        Wp[idx] = rne_bf16(v);
        return;
    }
    b -= nwp;
    {
        int n = b * 256 + threadIdx.x;
        if (n >= nN) return;
        int bb = batch[n];
        if (n == 0) {
            for (int g = 0; g <= bb; ++g) gstart[g] = 0;
        } else {
            int bp = batch[n - 1];
            for (int g = bp + 1; g <= bb; ++g) gstart[g] = n;
        }
        if (n == nN - 1) {
            for (int g = bb + 1; g <= nG; ++g) gstart[g] = nN;
        }
    }
}

// ---------------- fused RGCN conv layer (bf16 in / bf16 out) ----------------
// Phase 1: wave-level start4 prefetch (33 scalars -> s_load_dwordx16),
// per node ONE 32-deep gather batch typically (full 32-batches for high
// degree + one predicated). Straight-line single-buffer batches (no
// loop-carried arrays -> no scratch). Relation routing via SGPR-mask FMAC.
// A-tile LDS layout: (n, k) at n*320 + (kc&~7)*8 + (((kc&7)^(n&7))*8) + (k&7).

__global__ __launch_bounds__(256, 8) void k_conv(
        const unsigned short* __restrict__ hin, unsigned short* __restrict__ hout,
        const int* __restrict__ elist, const int* __restrict__ start4,
        const unsigned short* __restrict__ Wp, const float* __restrict__ bias, int nN) {
    __shared__ unsigned short A2[TILE * KDIM];  // 20 KB -> 8 blocks/CU
    const int tid = threadIdx.x;
    const int lane = tid & 63;
    const int wvs = __builtin_amdgcn_readfirstlane(tid >> 6);
    const int wv = tid >> 6;
    const int tile = blockIdx.x * TILE;

    // wave-level prefetch of this wave's 8 nodes' CSR bounds (33 contiguous ints)
    const int sbase = (tile + wvs * 8) * 4;
    const int smax = nN * 4;
    int s4[33];
#pragma unroll
    for (int i = 0; i < 33; ++i) {
        int idx = sbase + i;
        s4[i] = __builtin_amdgcn_readfirstlane(start4[(idx < smax) ? idx : smax]);
    }

#pragma unroll
    for (int jj = 0; jj < 8; ++jj) {
        const int nl = wvs * 8 + jj;
        const int n = tile + nl;
        unsigned short* Arow = &A2[nl * KDIM];
        const int sw = (((lane >> 3) ^ (nl & 7)) << 3) + (lane & 7);
        if (n >= nN) {
#pragma unroll
            for (int seg = 0; seg < 5; ++seg) Arow[seg * 64 + sw] = 0;
            continue;
        }
        const int e0 = s4[jj * 4 + 0];
        const int e1 = s4[jj * 4 + 1];
        const int e2 = s4[jj * 4 + 2];
        const int e3 = s4[jj * 4 + 3];
        const int e4 = s4[jj * 4 + 4];

        unsigned short selfb = hin[((size_t)n << 6) + lane];
        float S0 = 0.f, S1 = 0.f, S2 = 0.f, S3 = 0.f;
        int p = e0;

        // full 32-deep batches (only for degree > 32)
        for (; p + 32 <= e4; p += 32) {
            int q[32];
#pragma unroll
            for (int u = 0; u < 32; ++u)
                q[u] = __builtin_amdgcn_readfirstlane(elist[p + u]);
            unsigned short vb[32];
#pragma unroll
            for (int u = 0; u < 32; ++u)
                vb[u] = hin[((size_t)q[u] << 6) + lane];
            __builtin_amdgcn_sched_barrier(0);
#pragma unroll
            for (int u = 0; u < 32; ++u) {
                float t = bf16_f(vb[u]);
                int qq = p + u;
                S0 += t;
                S1 = fmaf(t, SMASK(qq >= e1), S1);
                S2 = fmaf(t, SMASK(qq >= e2), S2);
                S3 = fmaf(t, SMASK(qq >= e3), S3);
            }
        }
        // one predicated 32-deep tail batch (covers the typical whole node)
        if (p < e4) {
            int q[32];
#pragma unroll
            for (int u = 0; u < 32; ++u) {
                int qq = p + u;
                int qc = (qq < e4) ? qq : (e4 - 1);
                q[u] = __builtin_amdgcn_readfirstlane(elist[qc]);
            }
            unsigned short vb[32];
#pragma unroll
            for (int u = 0; u < 32; ++u)
                vb[u] = hin[((size_t)q[u] << 6) + lane];
            __builtin_amdgcn_sched_barrier(0);
#pragma unroll
            for (int u = 0; u < 32; ++u) {
                int qq = p + u;
                float t = bf16_f(vb[u]) * SMASK(qq < e4);
                S0 += t;
                S1 = fmaf(t, SMASK(qq >= e1), S1);
                S2 = fmaf(t, SMASK(qq >= e2), S2);
                S3 = fmaf(t, SMASK(qq >= e3), S3);
            }
        }

        int c0 = e1 - e0, c1 = e2 - e1, c2 = e3 - e2, c3 = e4 - e3;
        float a0 = (S0 - S1) * ((c0 > 0) ? 1.0f / (float)c0 : 0.f);
        float a1 = (S1 - S2) * ((c1 > 0) ? 1.0f / (float)c1 : 0.f);
        float a2 = (S2 - S3) * ((c2 > 0) ? 1.0f / (float)c2 : 0.f);
        float a3 = S3 * ((c3 > 0) ? 1.0f / (float)c3 : 0.f);
        Arow[0   + sw] = rne_bf16(a0);
        Arow[64  + sw] = rne_bf16(a1);
        Arow[128 + sw] = rne_bf16(a2);
        Arow[192 + sw] = rne_bf16(a3);
        Arow[256 + sw] = selfb;
    }
    __syncthreads();

    // phase 2: C[32 x 64] = A[32 x 320] * W[320 x 64] via mfma_f32_16x16x32_bf16.
    const int mt = wv & 1;
    const int ntb = (wv >> 1) << 1;
    const int nloc = mt * 16 + (lane & 15);
    f32x4 acc0 = {0.f, 0.f, 0.f, 0.f};
    f32x4 acc1 = {0.f, 0.f, 0.f, 0.f};
    const unsigned short* wp0 = Wp + ((size_t)(ntb * 10) * 64 + lane) * 8;
    const unsigned short* wp1 = Wp + ((size_t)((ntb + 1) * 10) * 64 + lane) * 8;
#pragma unroll 2
    for (int ks = 0; ks < 10; ++ks) {
        int kc = ks * 4 + (lane >> 4);
        int swz = (kc & ~7) | ((kc & 7) ^ (lane & 7));
        short8 a = *reinterpret_cast<const short8*>(&A2[nloc * KDIM + swz * 8]);
        short8 b0 = *reinterpret_cast<const short8*>(&wp0[ks * 512]);
        short8 b1 = *reinterpret_cast<const short8*>(&wp1[ks * 512]);
        acc0 = __builtin_amdgcn_mfma_f32_16x16x32_bf16(a, b0, acc0, 0, 0, 0);
        acc1 = __builtin_amdgcn_mfma_f32_16x16x32_bf16(a, b1, acc1, 0, 0, 0);
    }
    const int h0 = ntb * 16 + (lane & 15);
    const int nr = tile + mt * 16 + ((lane >> 4) << 2);
    const float bb0 = bias[h0];
    const float bb1 = bias[h0 + 16];
#pragma unroll
    for (int r = 0; r < 4; ++r) {
        int n = nr + r;
        if (n < nN) {
            hout[(size_t)n * 64 + h0]      = rne_bf16(fmaxf(acc0[r] + bb0, 0.f));
            hout[(size_t)n * 64 + h0 + 16] = rne_bf16(fmaxf(acc1[r] + bb1, 0.f));
        }
    }
}

// ---------------- fused mean-pool + MLP ----------------

__global__ void k_poolmlp(const unsigned short* __restrict__ h,
                          const int* __restrict__ gstart,
                          const float* __restrict__ w1, const float* __restrict__ b1,
                          const float* __restrict__ w2, const float* __restrict__ b2,
                          float* __restrict__ out) {
    __shared__ float red[4][64];
    __shared__ float sg[64];
    __shared__ float sh[64];
    int g = blockIdx.x;
    int t = threadIdx.x;
    int f = t & 63;
    int sl = t >> 6;
    int s = gstart[g], e = gstart[g + 1];
    float acc = 0.f;
    for (int n = s + sl; n < e; n += 4)
        acc += bf16_f(h[(size_t)n * 64 + f]);
    red[sl][f] = acc;
    __syncthreads();
    if (sl == 0) {
        int c = e - s;
        float m = (red[0][f] + red[1][f] + red[2][f] + red[3][f]) /
                  (float)((c > 0) ? c : 1);
        sg[f] = m;
    }
    __syncthreads();
    if (sl == 0) {
        float a = b1[f];
#pragma unroll 16
        for (int k = 0; k < 64; ++k) a += sg[k] * w1[k * 64 + f];
        sh[f] = fmaxf(a, 0.f);
    }
    __syncthreads();
    if (t < 10) {
        float o = b2[t];
#pragma unroll 16
        for (int k = 0; k < 64; ++k) o += sh[k] * w2[k * 10 + t];
        out[g * 10 + t] = o;
    }
}

// ---------------- launch ----------------

extern "C" void kernel_launch(void* const* d_in, const int* in_sizes, int n_in,
                              void* d_out, int out_size, void* d_ws, size_t ws_size,
                              hipStream_t stream) {
    const float* x     = (const float*)d_in[0];
    const int*   ei    = (const int*)d_in[1];
    const int*   et    = (const int*)d_in[2];
    const int*   batch = (const int*)d_in[3];
    const float* W1    = (const float*)d_in[4];
    const float* root1 = (const float*)d_in[5];
    const float* b1    = (const float*)d_in[6];
    const float* Wl    = (const float*)d_in[7];
    const float* rootl = (const float*)d_in[8];
    const float* bl    = (const float*)d_in[9];
    const float* l1w   = (const float*)d_in[10];
    const float* l1b   = (const float*)d_in[11];
    const float* l2w   = (const float*)d_in[12];
    const float* l2b   = (const float*)d_in[13];
    float* out = (float*)d_out;

    const int N = in_sizes[3];
    const int E = in_sizes[2];
    const int G = out_size / 10;
    const int M = 4 * N;

    const int* src = ei;
    const int* dst = ei + E;

    char* base = (char*)d_ws;
    size_t off = 0;
    auto carve = [&](size_t bytes) {
        char* p = base + off;
        off = (off + bytes + 511) & ~(size_t)511;
        return p;
    };
    int*   cnt4    = (int*)carve((size_t)M * 4);
    int*   start4  = (int*)carve((size_t)(M + 1) * 4);
    int*   rank    = (int*)carve((size_t)E * 4);
    int*   elist   = (int*)carve((size_t)E * 4);
    int*   bsum    = (int*)carve(512 * 4);
    int*   boff    = (int*)carve(512 * 4);
    unsigned short* Wpack = (unsigned short*)carve((size_t)3 * 320 * 64 * 2);
    unsigned short* xb    = (unsigned short*)carve((size_t)N * 64 * 2);
    unsigned short* hb_a  = (unsigned short*)carve((size_t)N * 64 * 2);
    unsigned short* hb_b  = (unsigned short*)carve((size_t)N * 64 * 2);
    int*   gstart  = (int*)carve((size_t)(G + 1) * 4);
    (void)ws_size;

    hipMemsetAsync(cnt4, 0, (size_t)M * 4, stream);

    const int necnt = (E + 255) / 256;
    const int ncvt = (N * 64 / 4 + 255) / 256;
    const int nwp  = (3 * 320 * 64 + 255) / 256;
    const int ngb  = (N + 255) / 256;
    k_prep<<<necnt + ncvt + nwp + ngb, 256, 0, stream>>>(
        dst, et, cnt4, rank, E, necnt,
        x, xb, ncvt, W1, root1, Wl, rootl, Wpack, nwp,
        batch, gstart, N, G);

    int nb = (M + 1023) / 1024;
    k_scan1<<<nb, 256, 0, stream>>>(cnt4, start4, bsum, M);
    k_scan2<<<1, 512, 0, stream>>>(bsum, boff, nb);
    k_scan3<<<(M + 1 + 255) / 256, 256, 0, stream>>>(start4, boff, M, E);
    k_fill<<<(E + 255) / 256, 256, 0, stream>>>(src, dst, et, start4, rank, elist, E);

    const int cb = (N + TILE - 1) / TILE;
    const int WSTRIDE = 320 * 64;
    k_conv<<<cb, 256, 0, stream>>>(xb,   hb_a, elist, start4, Wpack,               b1,      N);
    k_conv<<<cb, 256, 0, stream>>>(hb_a, hb_b, elist, start4, Wpack + WSTRIDE,     bl,      N);
    k_conv<<<cb, 256, 0, stream>>>(hb_b, hb_a, elist, start4, Wpack + 2 * WSTRIDE, bl + 64, N);

    k_poolmlp<<<G, 256, 0, stream>>>(hb_a, gstart, l1w, l1b, l2w, l2b, out);
}

// Round 13
// 397.554 us; speedup vs baseline: 1.2761x; 1.2761x over previous
//
#include <hip/hip_runtime.h>

#define TILE 32
#define KDIM 320
#define EBCAP 512

typedef __attribute__((ext_vector_type(8))) short short8;
typedef __attribute__((ext_vector_type(4))) float f32x4;

__device__ inline unsigned short rne_bf16(float f) {
    union { float f; unsigned u; } x;
    x.f = f;
    unsigned r = (x.u + 0x7FFF + ((x.u >> 16) & 1)) >> 16;
    return (unsigned short)r;
}

__device__ inline float bf16_f(unsigned short v) {
    union { unsigned u; float f; } x;
    x.u = ((unsigned)v) << 16;
    return x.f;
}

// scalar {1.0f, 0.0f} mask in an SGPR (condition is wave-uniform)
#define SMASK(cond) __int_as_float(__builtin_amdgcn_readfirstlane((cond) ? 0x3f800000 : 0))

// ---------------- scans ----------------

__global__ void k_scan1(const int* __restrict__ in, int* __restrict__ out,
                        int* __restrict__ bsum, int M) {
    __shared__ int s[256];
    int t = threadIdx.x;
    int base = blockIdx.x * 1024 + t * 4;
    int v0 = (base + 0 < M) ? in[base + 0] : 0;
    int v1 = (base + 1 < M) ? in[base + 1] : 0;
    int v2 = (base + 2 < M) ? in[base + 2] : 0;
    int v3 = (base + 3 < M) ? in[base + 3] : 0;
    int ts = v0 + v1 + v2 + v3;
    s[t] = ts;
    __syncthreads();
    for (int off = 1; off < 256; off <<= 1) {
        int x = (t >= off) ? s[t - off] : 0;
        __syncthreads();
        s[t] += x;
        __syncthreads();
    }
    int excl = (t == 0) ? 0 : s[t - 1];
    if (t == 255) bsum[blockIdx.x] = s[255];
    if (base + 0 < M) out[base + 0] = excl;
    if (base + 1 < M) out[base + 1] = excl + v0;
    if (base + 2 < M) out[base + 2] = excl + v0 + v1;
    if (base + 3 < M) out[base + 3] = excl + v0 + v1 + v2;
}

__global__ void k_scan2(const int* __restrict__ bsum, int* __restrict__ boff, int nb) {
    __shared__ int s[512];
    int t = threadIdx.x;
    s[t] = (t < nb) ? bsum[t] : 0;
    __syncthreads();
    for (int off = 1; off < 512; off <<= 1) {
        int x = (t >= off) ? s[t - off] : 0;
        __syncthreads();
        s[t] += x;
        __syncthreads();
    }
    if (t < nb) boff[t] = (t == 0) ? 0 : s[t - 1];
}

__global__ void k_scan3(int* __restrict__ out, const int* __restrict__ boff, int M, int E) {
    int i = blockIdx.x * 256 + threadIdx.x;
    if (i < M) out[i] += boff[i >> 10];
    else if (i == M) out[M] = E;
}

__global__ void k_fill(const int* __restrict__ src, const int* __restrict__ dst,
                       const int* __restrict__ typ, const int* __restrict__ start4,
                       const int* __restrict__ rank, int* __restrict__ elist, int E) {
    int e = blockIdx.x * 256 + threadIdx.x;
    if (e < E) {
        int seg = dst[e] * 4 + typ[e];
        elist[start4[seg] + rank[e]] = src[e];
    }
}

// ---------------- fused prep: edge count/rank | x->bf16 | weight pack | graph bounds ----

__global__ void k_prep(const int* __restrict__ dst, const int* __restrict__ typ,
                       int* __restrict__ cnt4, int* __restrict__ rank, int E, int necnt,
                       const float* __restrict__ x, unsigned short* __restrict__ xb, int ncvt,
                       const float* __restrict__ W1, const float* __restrict__ root1,
                       const float* __restrict__ Wl, const float* __restrict__ rootl,
                       unsigned short* __restrict__ Wp, int nwp,
                       const int* __restrict__ batch, int* __restrict__ gstart,
                       int nN, int nG) {
    int b = blockIdx.x;
    if (b < necnt) {
        int e = b * 256 + threadIdx.x;
        if (e < E) {
            int seg = dst[e] * 4 + typ[e];
            rank[e] = atomicAdd(&cnt4[seg], 1);
        }
        return;
    }
    b -= necnt;
    if (b < ncvt) {
        int i = (b * 256 + threadIdx.x) * 4;
        float4 v = *reinterpret_cast<const float4*>(&x[i]);
        ushort4 o;
        o.x = rne_bf16(v.x); o.y = rne_bf16(v.y);
        o.z = rne_bf16(v.z); o.w = rne_bf16(v.w);
        *reinterpret_cast<ushort4*>(&xb[i]) = o;
        return;
    }
    b -= ncvt;
    if (b < nwp) {
        int idx = b * 256 + threadIdx.x;
        const int TOT = 3 * 320 * 64;
        if (idx >= TOT) return;
        int j = idx & 7;
        int lane = (idx >> 3) & 63;
        int t = idx >> 9;
        int ks = t % 10;
        int lnt = t / 10;
        int nt = lnt & 3;
        int layer = lnt >> 2;
        int k = ks * 32 + ((lane >> 4) << 3) + j;
        int h = nt * 16 + (lane & 15);
        float v;
        if (k < 256) {
            v = (layer == 0) ? W1[k * 64 + h] : Wl[(layer - 1) * 16384 + k * 64 + h];
        } else {
            v = (layer == 0) ? root1[(k - 256) * 64 + h]
                             : rootl[(layer - 1) * 4096 + (k - 256) * 64 + h];
        }
        Wp[idx] = rne_bf16(v);
        return;
    }
    b -= nwp;
    {
        int n = b * 256 + threadIdx.x;
        if (n >= nN) return;
        int bb = batch[n];
        if (n == 0) {
            for (int g = 0; g <= bb; ++g) gstart[g] = 0;
        } else {
            int bp = batch[n - 1];
            for (int g = bp + 1; g <= bb; ++g) gstart[g] = n;
        }
        if (n == nN - 1) {
            for (int g = bb + 1; g <= nG; ++g) gstart[g] = nN;
        }
    }
}

// ---------------- fused RGCN conv layer (bf16 in / bf16 out) ----------------
// Phase 1: per-wave CSR bounds prefetched to SGPRs; the wave's contiguous
// elist range staged to LDS once (coalesced). Per 16-edge batch: indices via
// cheap ds_read broadcast -> readfirstlane -> saddr gathers. Straight-line
// single-buffer batches (depth 16 fits the VGPR budget; r11/r12 lesson).
// A-tile LDS layout: (n, k) at n*320 + (kc&~7)*8 + (((kc&7)^(n&7))*8) + (k&7).

__global__ __launch_bounds__(256, 5) void k_conv(
        const unsigned short* __restrict__ hin, unsigned short* __restrict__ hout,
        const int* __restrict__ elist, const int* __restrict__ start4,
        const unsigned short* __restrict__ Wp, const float* __restrict__ bias, int nN) {
    __shared__ unsigned short A2[TILE * KDIM];  // 20 KB
    __shared__ int EB[4][EBCAP];                // 8 KB  -> 28 KB total, 5 blocks/CU
    const int tid = threadIdx.x;
    const int lane = tid & 63;
    const int wvs = __builtin_amdgcn_readfirstlane(tid >> 6);
    const int wv = tid >> 6;
    const int tile = blockIdx.x * TILE;

    // wave-level prefetch of this wave's 8 nodes' CSR bounds (33 contiguous ints)
    const int sbase = (tile + wvs * 8) * 4;
    const int smax = nN * 4;
    int s4[33];
#pragma unroll
    for (int i = 0; i < 33; ++i) {
        int idx = sbase + i;
        s4[i] = __builtin_amdgcn_readfirstlane(start4[(idx < smax) ? idx : smax]);
    }
    const int we0 = s4[0];
    const int wcnt = s4[32] - we0;

    // stage the wave's contiguous elist range into LDS (coalesced)
    for (int k = lane; k < wcnt && k < EBCAP; k += 64)
        EB[wvs][k] = elist[we0 + k];
    // (own-wave LDS readback ordered by compiler-inserted lgkmcnt)

    const bool fast = (tile + TILE <= nN) && (wcnt <= EBCAP);

    if (fast) {
#pragma unroll
        for (int jj = 0; jj < 8; ++jj) {
            const int nl = wvs * 8 + jj;
            const int n = tile + nl;
            unsigned short* Arow = &A2[nl * KDIM];
            const int sw = (((lane >> 3) ^ (nl & 7)) << 3) + (lane & 7);
            const int e0 = s4[jj * 4 + 0];
            const int e1 = s4[jj * 4 + 1];
            const int e2 = s4[jj * 4 + 2];
            const int e3 = s4[jj * 4 + 3];
            const int e4 = s4[jj * 4 + 4];

            unsigned short selfb = hin[((size_t)n << 6) + lane];
            float S0 = 0.f, S1 = 0.f, S2 = 0.f, S3 = 0.f;
            int p = e0;

            for (; p + 16 <= e4; p += 16) {
                const int off = p - we0;
                int q[16];
#pragma unroll
                for (int u = 0; u < 16; ++u)
                    q[u] = __builtin_amdgcn_readfirstlane(EB[wvs][off + u]);
                unsigned short vb[16];
#pragma unroll
                for (int u = 0; u < 16; ++u)
                    vb[u] = hin[((size_t)q[u] << 6) + lane];
                __builtin_amdgcn_sched_barrier(0);
#pragma unroll
                for (int u = 0; u < 16; ++u) {
                    float t = bf16_f(vb[u]);
                    int qq = p + u;
                    S0 += t;
                    S1 = fmaf(t, SMASK(qq >= e1), S1);
                    S2 = fmaf(t, SMASK(qq >= e2), S2);
                    S3 = fmaf(t, SMASK(qq >= e3), S3);
                }
            }
            if (p < e4) {
                int q[16];
#pragma unroll
                for (int u = 0; u < 16; ++u) {
                    int qq = p + u;
                    int qc = ((qq < e4) ? qq : (e4 - 1)) - we0;
                    q[u] = __builtin_amdgcn_readfirstlane(EB[wvs][qc]);
                }
                unsigned short vb[16];
#pragma unroll
                for (int u = 0; u < 16; ++u)
                    vb[u] = hin[((size_t)q[u] << 6) + lane];
                __builtin_amdgcn_sched_barrier(0);
#pragma unroll
                for (int u = 0; u < 16; ++u) {
                    int qq = p + u;
                    float t = bf16_f(vb[u]) * SMASK(qq < e4);
                    S0 += t;
                    S1 = fmaf(t, SMASK(qq >= e1), S1);
                    S2 = fmaf(t, SMASK(qq >= e2), S2);
                    S3 = fmaf(t, SMASK(qq >= e3), S3);
                }
            }

            int c0 = e1 - e0, c1 = e2 - e1, c2 = e3 - e2, c3 = e4 - e3;
            float a0 = (S0 - S1) * ((c0 > 0) ? 1.0f / (float)c0 : 0.f);
            float a1 = (S1 - S2) * ((c1 > 0) ? 1.0f / (float)c1 : 0.f);
            float a2 = (S2 - S3) * ((c2 > 0) ? 1.0f / (float)c2 : 0.f);
            float a3 = S3 * ((c3 > 0) ? 1.0f / (float)c3 : 0.f);
            Arow[0   + sw] = rne_bf16(a0);
            Arow[64  + sw] = rne_bf16(a1);
            Arow[128 + sw] = rne_bf16(a2);
            Arow[192 + sw] = rne_bf16(a3);
            Arow[256 + sw] = selfb;
        }
    } else {
        // slow path: bounds-checked, global elist (readfirstlane/SMEM)
        for (int jj = 0; jj < 8; ++jj) {
            const int nl = wvs * 8 + jj;
            const int n = tile + nl;
            unsigned short* Arow = &A2[nl * KDIM];
            const int sw = (((lane >> 3) ^ (nl & 7)) << 3) + (lane & 7);
            if (n >= nN) {
#pragma unroll
                for (int seg = 0; seg < 5; ++seg) Arow[seg * 64 + sw] = 0;
                continue;
            }
            const int e0 = s4[jj * 4 + 0];
            const int e1 = s4[jj * 4 + 1];
            const int e2 = s4[jj * 4 + 2];
            const int e3 = s4[jj * 4 + 3];
            const int e4 = s4[jj * 4 + 4];

            unsigned short selfb = hin[((size_t)n << 6) + lane];
            float S0 = 0.f, S1 = 0.f, S2 = 0.f, S3 = 0.f;
            int p = e0;
            for (; p + 16 <= e4; p += 16) {
                int q[16];
#pragma unroll
                for (int u = 0; u < 16; ++u)
                    q[u] = __builtin_amdgcn_readfirstlane(elist[p + u]);
                unsigned short vb[16];
#pragma unroll
                for (int u = 0; u < 16; ++u)
                    vb[u] = hin[((size_t)q[u] << 6) + lane];
                __builtin_amdgcn_sched_barrier(0);
#pragma unroll
                for (int u = 0; u < 16; ++u) {
                    float t = bf16_f(vb[u]);
                    int qq = p + u;
                    S0 += t;
                    S1 = fmaf(t, SMASK(qq >= e1), S1);
                    S2 = fmaf(t, SMASK(qq >= e2), S2);
                    S3 = fmaf(t, SMASK(qq >= e3), S3);
                }
            }
            if (p < e4) {
                int q[16];
#pragma unroll
                for (int u = 0; u < 16; ++u) {
                    int qq = p + u;
                    int qc = (qq < e4) ? qq : (e4 - 1);
                    q[u] = __builtin_amdgcn_readfirstlane(elist[qc]);
                }
                unsigned short vb[16];
#pragma unroll
                for (int u = 0; u < 16; ++u)
                    vb[u] = hin[((size_t)q[u] << 6) + lane];
                __builtin_amdgcn_sched_barrier(0);
#pragma unroll
                for (int u = 0; u < 16; ++u) {
                    int qq = p + u;
                    float t = bf16_f(vb[u]) * SMASK(qq < e4);
                    S0 += t;
                    S1 = fmaf(t, SMASK(qq >= e1), S1);
                    S2 = fmaf(t, SMASK(qq >= e2), S2);
                    S3 = fmaf(t, SMASK(qq >= e3), S3);
                }
            }

            int c0 = e1 - e0, c1 = e2 - e1, c2 = e3 - e2, c3 = e4 - e3;
            float a0 = (S0 - S1) * ((c0 > 0) ? 1.0f / (float)c0 : 0.f);
            float a1 = (S1 - S2) * ((c1 > 0) ? 1.0f / (float)c1 : 0.f);
            float a2 = (S2 - S3) * ((c2 > 0) ? 1.0f / (float)c2 : 0.f);
            float a3 = S3 * ((c3 > 0) ? 1.0f / (float)c3 : 0.f);
            Arow[0   + sw] = rne_bf16(a0);
            Arow[64  + sw] = rne_bf16(a1);
            Arow[128 + sw] = rne_bf16(a2);
            Arow[192 + sw] = rne_bf16(a3);
            Arow[256 + sw] = selfb;
        }
    }
    __syncthreads();

    // phase 2: C[32 x 64] = A[32 x 320] * W[320 x 64] via mfma_f32_16x16x32_bf16.
    const int mt = wv & 1;
    const int ntb = (wv >> 1) << 1;
    const int nloc = mt * 16 + (lane & 15);
    f32x4 acc0 = {0.f, 0.f, 0.f, 0.f};
    f32x4 acc1 = {0.f, 0.f, 0.f, 0.f};
    const unsigned short* wp0 = Wp + ((size_t)(ntb * 10) * 64 + lane) * 8;
    const unsigned short* wp1 = Wp + ((size_t)((ntb + 1) * 10) * 64 + lane) * 8;
#pragma unroll 2
    for (int ks = 0; ks < 10; ++ks) {
        int kc = ks * 4 + (lane >> 4);
        int swz = (kc & ~7) | ((kc & 7) ^ (lane & 7));
        short8 a = *reinterpret_cast<const short8*>(&A2[nloc * KDIM + swz * 8]);
        short8 b0 = *reinterpret_cast<const short8*>(&wp0[ks * 512]);
        short8 b1 = *reinterpret_cast<const short8*>(&wp1[ks * 512]);
        acc0 = __builtin_amdgcn_mfma_f32_16x16x32_bf16(a, b0, acc0, 0, 0, 0);
        acc1 = __builtin_amdgcn_mfma_f32_16x16x32_bf16(a, b1, acc1, 0, 0, 0);
    }
    const int h0 = ntb * 16 + (lane & 15);
    const int nr = tile + mt * 16 + ((lane >> 4) << 2);
    const float bb0 = bias[h0];
    const float bb1 = bias[h0 + 16];
#pragma unroll
    for (int r = 0; r < 4; ++r) {
        int n = nr + r;
        if (n < nN) {
            hout[(size_t)n * 64 + h0]      = rne_bf16(fmaxf(acc0[r] + bb0, 0.f));
            hout[(size_t)n * 64 + h0 + 16] = rne_bf16(fmaxf(acc1[r] + bb1, 0.f));
        }
    }
}

// ---------------- fused mean-pool + MLP ----------------

__global__ void k_poolmlp(const unsigned short* __restrict__ h,
                          const int* __restrict__ gstart,
                          const float* __restrict__ w1, const float* __restrict__ b1,
                          const float* __restrict__ w2, const float* __restrict__ b2,
                          float* __restrict__ out) {
    __shared__ float red[4][64];
    __shared__ float sg[64];
    __shared__ float sh[64];
    int g = blockIdx.x;
    int t = threadIdx.x;
    int f = t & 63;
    int sl = t >> 6;
    int s = gstart[g], e = gstart[g + 1];
    float acc = 0.f;
    for (int n = s + sl; n < e; n += 4)
        acc += bf16_f(h[(size_t)n * 64 + f]);
    red[sl][f] = acc;
    __syncthreads();
    if (sl == 0) {
        int c = e - s;
        float m = (red[0][f] + red[1][f] + red[2][f] + red[3][f]) /
                  (float)((c > 0) ? c : 1);
        sg[f] = m;
    }
    __syncthreads();
    if (sl == 0) {
        float a = b1[f];
#pragma unroll 16
        for (int k = 0; k < 64; ++k) a += sg[k] * w1[k * 64 + f];
        sh[f] = fmaxf(a, 0.f);
    }
    __syncthreads();
    if (t < 10) {
        float o = b2[t];
#pragma unroll 16
        for (int k = 0; k < 64; ++k) o += sh[k] * w2[k * 10 + t];
        out[g * 10 + t] = o;
    }
}

// ---------------- launch ----------------

extern "C" void kernel_launch(void* const* d_in, const int* in_sizes, int n_in,
                              void* d_out, int out_size, void* d_ws, size_t ws_size,
                              hipStream_t stream) {
    const float* x     = (const float*)d_in[0];
    const int*   ei    = (const int*)d_in[1];
    const int*   et    = (const int*)d_in[2];
    const int*   batch = (const int*)d_in[3];
    const float* W1    = (const float*)d_in[4];
    const float* root1 = (const float*)d_in[5];
    const float* b1    = (const float*)d_in[6];
    const float* Wl    = (const float*)d_in[7];
    const float* rootl = (const float*)d_in[8];
    const float* bl    = (const float*)d_in[9];
    const float* l1w   = (const float*)d_in[10];
    const float* l1b   = (const float*)d_in[11];
    const float* l2w   = (const float*)d_in[12];
    const float* l2b   = (const float*)d_in[13];
    float* out = (float*)d_out;

    const int N = in_sizes[3];
    const int E = in_sizes[2];
    const int G = out_size / 10;
    const int M = 4 * N;

    const int* src = ei;
    const int* dst = ei + E;

    char* base = (char*)d_ws;
    size_t off = 0;
    auto carve = [&](size_t bytes) {
        char* p = base + off;
        off = (off + bytes + 511) & ~(size_t)511;
        return p;
    };
    int*   cnt4    = (int*)carve((size_t)M * 4);
    int*   start4  = (int*)carve((size_t)(M + 1) * 4);
    int*   rank    = (int*)carve((size_t)E * 4);
    int*   elist   = (int*)carve((size_t)E * 4);
    int*   bsum    = (int*)carve(512 * 4);
    int*   boff    = (int*)carve(512 * 4);
    unsigned short* Wpack = (unsigned short*)carve((size_t)3 * 320 * 64 * 2);
    unsigned short* xb    = (unsigned short*)carve((size_t)N * 64 * 2);
    unsigned short* hb_a  = (unsigned short*)carve((size_t)N * 64 * 2);
    unsigned short* hb_b  = (unsigned short*)carve((size_t)N * 64 * 2);
    int*   gstart  = (int*)carve((size_t)(G + 1) * 4);
    (void)ws_size;

    hipMemsetAsync(cnt4, 0, (size_t)M * 4, stream);

    const int necnt = (E + 255) / 256;
    const int ncvt = (N * 64 / 4 + 255) / 256;
    const int nwp  = (3 * 320 * 64 + 255) / 256;
    const int ngb  = (N + 255) / 256;
    k_prep<<<necnt + ncvt + nwp + ngb, 256, 0, stream>>>(
        dst, et, cnt4, rank, E, necnt,
        x, xb, ncvt, W1, root1, Wl, rootl, Wpack, nwp,
        batch, gstart, N, G);

    int nb = (M + 1023) / 1024;
    k_scan1<<<nb, 256, 0, stream>>>(cnt4, start4, bsum, M);
    k_scan2<<<1, 512, 0, stream>>>(bsum, boff, nb);
    k_scan3<<<(M + 1 + 255) / 256, 256, 0, stream>>>(start4, boff, M, E);
    k_fill<<<(E + 255) / 256, 256, 0, stream>>>(src, dst, et, start4, rank, elist, E);

    const int cb = (N + TILE - 1) / TILE;
    const int WSTRIDE = 320 * 64;
    k_conv<<<cb, 256, 0, stream>>>(xb,   hb_a, elist, start4, Wpack,               b1,      N);
    k_conv<<<cb, 256, 0, stream>>>(hb_a, hb_b, elist, start4, Wpack + WSTRIDE,     bl,      N);
    k_conv<<<cb, 256, 0, stream>>>(hb_b, hb_a, elist, start4, Wpack + 2 * WSTRIDE, bl + 64, N);

    k_poolmlp<<<G, 256, 0, stream>>>(hb_a, gstart, l1w, l1b, l2w, l2b, out);
}

// Round 14
// 339.414 us; speedup vs baseline: 1.4947x; 1.1713x over previous
//
#include <hip/hip_runtime.h>

#define TILE 32
#define KDIM 320

typedef __attribute__((ext_vector_type(8))) short short8;
typedef __attribute__((ext_vector_type(4))) float f32x4;

__device__ inline unsigned short rne_bf16(float f) {
    union { float f; unsigned u; } x;
    x.f = f;
    unsigned r = (x.u + 0x7FFF + ((x.u >> 16) & 1)) >> 16;
    return (unsigned short)r;
}

__device__ inline float bf16_f(unsigned short v) {
    union { unsigned u; float f; } x;
    x.u = ((unsigned)v) << 16;
    return x.f;
}

// ---------------- scans ----------------

__global__ void k_scan1(const int* __restrict__ in, int* __restrict__ out,
                        int* __restrict__ bsum, int M) {
    __shared__ int s[256];
    int t = threadIdx.x;
    int base = blockIdx.x * 1024 + t * 4;
    int v0 = (base + 0 < M) ? in[base + 0] : 0;
    int v1 = (base + 1 < M) ? in[base + 1] : 0;
    int v2 = (base + 2 < M) ? in[base + 2] : 0;
    int v3 = (base + 3 < M) ? in[base + 3] : 0;
    int ts = v0 + v1 + v2 + v3;
    s[t] = ts;
    __syncthreads();
    for (int off = 1; off < 256; off <<= 1) {
        int x = (t >= off) ? s[t - off] : 0;
        __syncthreads();
        s[t] += x;
        __syncthreads();
    }
    int excl = (t == 0) ? 0 : s[t - 1];
    if (t == 255) bsum[blockIdx.x] = s[255];
    if (base + 0 < M) out[base + 0] = excl;
    if (base + 1 < M) out[base + 1] = excl + v0;
    if (base + 2 < M) out[base + 2] = excl + v0 + v1;
    if (base + 3 < M) out[base + 3] = excl + v0 + v1 + v2;
}

__global__ void k_scan2(const int* __restrict__ bsum, int* __restrict__ boff, int nb) {
    __shared__ int s[512];
    int t = threadIdx.x;
    s[t] = (t < nb) ? bsum[t] : 0;
    __syncthreads();
    for (int off = 1; off < 512; off <<= 1) {
        int x = (t >= off) ? s[t - off] : 0;
        __syncthreads();
        s[t] += x;
        __syncthreads();
    }
    if (t < nb) boff[t] = (t == 0) ? 0 : s[t - 1];
}

__global__ void k_scan3(int* __restrict__ out, const int* __restrict__ boff, int M, int E) {
    int i = blockIdx.x * 256 + threadIdx.x;
    if (i < M) out[i] += boff[i >> 10];
    else if (i == M) out[M] = E;
}

__global__ void k_fill(const int* __restrict__ src, const int* __restrict__ dst,
                       const int* __restrict__ typ, const int* __restrict__ start4,
                       const int* __restrict__ rank, int* __restrict__ elist, int E) {
    int e = blockIdx.x * 256 + threadIdx.x;
    if (e < E) {
        int seg = dst[e] * 4 + typ[e];
        elist[start4[seg] + rank[e]] = src[e];
    }
}

// ---------------- fused prep: edge count/rank | x->bf16 | weight pack | graph bounds ----

__global__ void k_prep(const int* __restrict__ dst, const int* __restrict__ typ,
                       int* __restrict__ cnt4, int* __restrict__ rank, int E, int necnt,
                       const float* __restrict__ x, unsigned short* __restrict__ xb, int ncvt,
                       const float* __restrict__ W1, const float* __restrict__ root1,
                       const float* __restrict__ Wl, const float* __restrict__ rootl,
                       unsigned short* __restrict__ Wp, int nwp,
                       const int* __restrict__ batch, int* __restrict__ gstart,
                       int nN, int nG) {
    int b = blockIdx.x;
    if (b < necnt) {
        int e = b * 256 + threadIdx.x;
        if (e < E) {
            int seg = dst[e] * 4 + typ[e];
            rank[e] = atomicAdd(&cnt4[seg], 1);
        }
        return;
    }
    b -= necnt;
    if (b < ncvt) {
        int i = (b * 256 + threadIdx.x) * 4;
        float4 v = *reinterpret_cast<const float4*>(&x[i]);
        ushort4 o;
        o.x = rne_bf16(v.x); o.y = rne_bf16(v.y);
        o.z = rne_bf16(v.z); o.w = rne_bf16(v.w);
        *reinterpret_cast<ushort4*>(&xb[i]) = o;
        return;
    }
    b -= ncvt;
    if (b < nwp) {
        int idx = b * 256 + threadIdx.x;
        const int TOT = 3 * 320 * 64;
        if (idx >= TOT) return;
        int j = idx & 7;
        int lane = (idx >> 3) & 63;
        int t = idx >> 9;
        int ks = t % 10;
        int lnt = t / 10;
        int nt = lnt & 3;
        int layer = lnt >> 2;
        int k = ks * 32 + ((lane >> 4) << 3) + j;
        int h = nt * 16 + (lane & 15);
        float v;
        if (k < 256) {
            v = (layer == 0) ? W1[k * 64 + h] : Wl[(layer - 1) * 16384 + k * 64 + h];
        } else {
            v = (layer == 0) ? root1[(k - 256) * 64 + h]
                             : rootl[(layer - 1) * 4096 + (k - 256) * 64 + h];
        }
        Wp[idx] = rne_bf16(v);
        return;
    }
    b -= nwp;
    {
        int n = b * 256 + threadIdx.x;
        if (n >= nN) return;
        int bb = batch[n];
        if (n == 0) {
            for (int g = 0; g <= bb; ++g) gstart[g] = 0;
        } else {
            int bp = batch[n - 1];
            for (int g = bp + 1; g <= bb; ++g) gstart[g] = n;
        }
        if (n == nN - 1) {
            for (int g = bb + 1; g <= nG; ++g) gstart[g] = nN;
        }
    }
}

// ---------------- fused RGCN conv layer (bf16 in / bf16 out) ----------------
// Phase 1, 4-edges-per-VMEM: 16 lanes per edge row (ushort4 = 8B/lane),
// so one gather instruction fetches 4 edges' rows (512B). Per 16-edge batch:
// 4 per-lane idx loads + 4 data loads (2 latency windows). Accumulators:
// 4 rel x 4 feat named floats; 2-step shfl_xor reduction per node; lanes
// 0-15 write final quads via ds_write_b64 into the swizzled A-tile.
// A-tile layout: (n, k) at n*320 + ((kc&~7) + ((kc&7)^(n&7)))*8 + (k&7).

#define CONSUME4(I, D)                                                         \
    do {                                                                       \
        float m0 = ((I) < e4) ? 1.f : 0.f;                                     \
        float m1 = ((I) >= e1) ? 1.f : 0.f;                                    \
        float m2 = ((I) >= e2) ? 1.f : 0.f;                                    \
        float m3 = ((I) >= e3) ? 1.f : 0.f;                                    \
        float t0 = bf16_f((D).x) * m0;                                         \
        float t1 = bf16_f((D).y) * m0;                                         \
        float t2 = bf16_f((D).z) * m0;                                         \
        float t3 = bf16_f((D).w) * m0;                                         \
        s00 += t0; s01 += t1; s02 += t2; s03 += t3;                            \
        s10 = fmaf(t0, m1, s10); s11 = fmaf(t1, m1, s11);                      \
        s12 = fmaf(t2, m1, s12); s13 = fmaf(t3, m1, s13);                      \
        s20 = fmaf(t0, m2, s20); s21 = fmaf(t1, m2, s21);                      \
        s22 = fmaf(t2, m2, s22); s23 = fmaf(t3, m2, s23);                      \
        s30 = fmaf(t0, m3, s30); s31 = fmaf(t1, m3, s31);                      \
        s32 = fmaf(t2, m3, s32); s33 = fmaf(t3, m3, s33);                      \
    } while (0)

#define RED2(v)                                                                \
    do {                                                                       \
        v += __shfl_xor(v, 16, 64);                                            \
        v += __shfl_xor(v, 32, 64);                                            \
    } while (0)

__global__ __launch_bounds__(256, 6) void k_conv(
        const unsigned short* __restrict__ hin, unsigned short* __restrict__ hout,
        const int* __restrict__ elist, const int* __restrict__ start4,
        const unsigned short* __restrict__ Wp, const float* __restrict__ bias, int nN) {
    __shared__ unsigned short A2[TILE * KDIM];  // 20 KB
    const int tid = threadIdx.x;
    const int lane = tid & 63;
    const int wvs = __builtin_amdgcn_readfirstlane(tid >> 6);
    const int wv = tid >> 6;
    const int tile = blockIdx.x * TILE;

    const int eg = lane >> 4;        // edge subgroup 0..3
    const int fo = (lane & 15) * 4;  // feature offset (ushorts) for data loads

    for (int jj = 0; jj < 8; ++jj) {
        const int nl = wvs * 8 + jj;
        const int n = tile + nl;
        unsigned short* Arow = &A2[nl * KDIM];
        const int sw = (((lane >> 3) ^ (nl & 7)) << 3) + (lane & 7);
        if (n >= nN) {
#pragma unroll
            for (int seg = 0; seg < 5; ++seg) Arow[seg * 64 + sw] = 0;
            continue;
        }
        const int e0 = __builtin_amdgcn_readfirstlane(start4[n * 4 + 0]);
        const int e1 = __builtin_amdgcn_readfirstlane(start4[n * 4 + 1]);
        const int e2 = __builtin_amdgcn_readfirstlane(start4[n * 4 + 2]);
        const int e3 = __builtin_amdgcn_readfirstlane(start4[n * 4 + 3]);
        const int e4 = __builtin_amdgcn_readfirstlane(start4[n * 4 + 4]);

        unsigned short selfb = hin[((size_t)n << 6) + lane];
        float s00 = 0.f, s01 = 0.f, s02 = 0.f, s03 = 0.f;
        float s10 = 0.f, s11 = 0.f, s12 = 0.f, s13 = 0.f;
        float s20 = 0.f, s21 = 0.f, s22 = 0.f, s23 = 0.f;
        float s30 = 0.f, s31 = 0.f, s32 = 0.f, s33 = 0.f;

        for (int p = e0; p < e4; p += 16) {
            // per-lane edge ids for the 4 subgroup loads (clamped for tail)
            int i0 = p + 0 + eg;
            int i1 = p + 4 + eg;
            int i2 = p + 8 + eg;
            int i3 = p + 12 + eg;
            int c0 = (i0 < e4) ? i0 : (e4 - 1);
            int c1 = (i1 < e4) ? i1 : (e4 - 1);
            int c2 = (i2 < e4) ? i2 : (e4 - 1);
            int c3 = (i3 < e4) ? i3 : (e4 - 1);
            int x0 = elist[c0];
            int x1 = elist[c1];
            int x2 = elist[c2];
            int x3 = elist[c3];
            ushort4 d0 = *reinterpret_cast<const ushort4*>(&hin[((size_t)x0 << 6) + fo]);
            ushort4 d1 = *reinterpret_cast<const ushort4*>(&hin[((size_t)x1 << 6) + fo]);
            ushort4 d2 = *reinterpret_cast<const ushort4*>(&hin[((size_t)x2 << 6) + fo]);
            ushort4 d3 = *reinterpret_cast<const ushort4*>(&hin[((size_t)x3 << 6) + fo]);
            __builtin_amdgcn_sched_barrier(0);
            CONSUME4(i0, d0);
            CONSUME4(i1, d1);
            CONSUME4(i2, d2);
            CONSUME4(i3, d3);
        }

        // cross-lane reduce over the 4 edge subgroups (xor 16, 32)
        RED2(s00); RED2(s01); RED2(s02); RED2(s03);
        RED2(s10); RED2(s11); RED2(s12); RED2(s13);
        RED2(s20); RED2(s21); RED2(s22); RED2(s23);
        RED2(s30); RED2(s31); RED2(s32); RED2(s33);

        int cA = e1 - e0, cB = e2 - e1, cC = e3 - e2, cD = e4 - e3;
        float iA = (cA > 0) ? 1.0f / (float)cA : 0.f;
        float iB = (cB > 0) ? 1.0f / (float)cB : 0.f;
        float iC = (cC > 0) ? 1.0f / (float)cC : 0.f;
        float iD = (cD > 0) ? 1.0f / (float)cD : 0.f;

        if (lane < 16) {
            const int half = lane & 1;
            const int kcs = lane >> 1;  // (lane&15)>>1
            ushort4 w;
            // rel 0
            w.x = rne_bf16((s00 - s10) * iA); w.y = rne_bf16((s01 - s11) * iA);
            w.z = rne_bf16((s02 - s12) * iA); w.w = rne_bf16((s03 - s13) * iA);
            {
                int kc = 0 * 8 + kcs;
                int off = ((kc & ~7) + ((kc & 7) ^ (nl & 7))) * 8 + half * 4;
                *reinterpret_cast<ushort4*>(&Arow[off]) = w;
            }
            // rel 1
            w.x = rne_bf16((s10 - s20) * iB); w.y = rne_bf16((s11 - s21) * iB);
            w.z = rne_bf16((s12 - s22) * iB); w.w = rne_bf16((s13 - s23) * iB);
            {
                int kc = 1 * 8 + kcs;
                int off = ((kc & ~7) + ((kc & 7) ^ (nl & 7))) * 8 + half * 4;
                *reinterpret_cast<ushort4*>(&Arow[off]) = w;
            }
            // rel 2
            w.x = rne_bf16((s20 - s30) * iC); w.y = rne_bf16((s21 - s31) * iC);
            w.z = rne_bf16((s22 - s32) * iC); w.w = rne_bf16((s23 - s33) * iC);
            {
                int kc = 2 * 8 + kcs;
                int off = ((kc & ~7) + ((kc & 7) ^ (nl & 7))) * 8 + half * 4;
                *reinterpret_cast<ushort4*>(&Arow[off]) = w;
            }
            // rel 3
            w.x = rne_bf16(s30 * iD); w.y = rne_bf16(s31 * iD);
            w.z = rne_bf16(s32 * iD); w.w = rne_bf16(s33 * iD);
            {
                int kc = 3 * 8 + kcs;
                int off = ((kc & ~7) + ((kc & 7) ^ (nl & 7))) * 8 + half * 4;
                *reinterpret_cast<ushort4*>(&Arow[off]) = w;
            }
        }
        Arow[256 + sw] = selfb;  // self row, all lanes
    }
    __syncthreads();

    // phase 2: C[32 x 64] = A[32 x 320] * W[320 x 64] via mfma_f32_16x16x32_bf16.
    const int mt = wv & 1;
    const int ntb = (wv >> 1) << 1;
    const int nloc = mt * 16 + (lane & 15);
    f32x4 acc0 = {0.f, 0.f, 0.f, 0.f};
    f32x4 acc1 = {0.f, 0.f, 0.f, 0.f};
    const unsigned short* wp0 = Wp + ((size_t)(ntb * 10) * 64 + lane) * 8;
    const unsigned short* wp1 = Wp + ((size_t)((ntb + 1) * 10) * 64 + lane) * 8;
#pragma unroll 2
    for (int ks = 0; ks < 10; ++ks) {
        int kc = ks * 4 + (lane >> 4);
        int swz = (kc & ~7) | ((kc & 7) ^ (lane & 7));
        short8 a = *reinterpret_cast<const short8*>(&A2[nloc * KDIM + swz * 8]);
        short8 b0 = *reinterpret_cast<const short8*>(&wp0[ks * 512]);
        short8 b1 = *reinterpret_cast<const short8*>(&wp1[ks * 512]);
        acc0 = __builtin_amdgcn_mfma_f32_16x16x32_bf16(a, b0, acc0, 0, 0, 0);
        acc1 = __builtin_amdgcn_mfma_f32_16x16x32_bf16(a, b1, acc1, 0, 0, 0);
    }
    const int h0 = ntb * 16 + (lane & 15);
    const int nr = tile + mt * 16 + ((lane >> 4) << 2);
    const float bb0 = bias[h0];
    const float bb1 = bias[h0 + 16];
#pragma unroll
    for (int r = 0; r < 4; ++r) {
        int n = nr + r;
        if (n < nN) {
            hout[(size_t)n * 64 + h0]      = rne_bf16(fmaxf(acc0[r] + bb0, 0.f));
            hout[(size_t)n * 64 + h0 + 16] = rne_bf16(fmaxf(acc1[r] + bb1, 0.f));
        }
    }
}

// ---------------- fused mean-pool + MLP ----------------

__global__ void k_poolmlp(const unsigned short* __restrict__ h,
                          const int* __restrict__ gstart,
                          const float* __restrict__ w1, const float* __restrict__ b1,
                          const float* __restrict__ w2, const float* __restrict__ b2,
                          float* __restrict__ out) {
    __shared__ float red[4][64];
    __shared__ float sg[64];
    __shared__ float sh[64];
    int g = blockIdx.x;
    int t = threadIdx.x;
    int f = t & 63;
    int sl = t >> 6;
    int s = gstart[g], e = gstart[g + 1];
    float acc = 0.f;
    for (int n = s + sl; n < e; n += 4)
        acc += bf16_f(h[(size_t)n * 64 + f]);
    red[sl][f] = acc;
    __syncthreads();
    if (sl == 0) {
        int c = e - s;
        float m = (red[0][f] + red[1][f] + red[2][f] + red[3][f]) /
                  (float)((c > 0) ? c : 1);
        sg[f] = m;
    }
    __syncthreads();
    if (sl == 0) {
        float a = b1[f];
#pragma unroll 16
        for (int k = 0; k < 64; ++k) a += sg[k] * w1[k * 64 + f];
        sh[f] = fmaxf(a, 0.f);
    }
    __syncthreads();
    if (t < 10) {
        float o = b2[t];
#pragma unroll 16
        for (int k = 0; k < 64; ++k) o += sh[k] * w2[k * 10 + t];
        out[g * 10 + t] = o;
    }
}

// ---------------- launch ----------------

extern "C" void kernel_launch(void* const* d_in, const int* in_sizes, int n_in,
                              void* d_out, int out_size, void* d_ws, size_t ws_size,
                              hipStream_t stream) {
    const float* x     = (const float*)d_in[0];
    const int*   ei    = (const int*)d_in[1];
    const int*   et    = (const int*)d_in[2];
    const int*   batch = (const int*)d_in[3];
    const float* W1    = (const float*)d_in[4];
    const float* root1 = (const float*)d_in[5];
    const float* b1    = (const float*)d_in[6];
    const float* Wl    = (const float*)d_in[7];
    const float* rootl = (const float*)d_in[8];
    const float* bl    = (const float*)d_in[9];
    const float* l1w   = (const float*)d_in[10];
    const float* l1b   = (const float*)d_in[11];
    const float* l2w   = (const float*)d_in[12];
    const float* l2b   = (const float*)d_in[13];
    float* out = (float*)d_out;

    const int N = in_sizes[3];
    const int E = in_sizes[2];
    const int G = out_size / 10;
    const int M = 4 * N;

    const int* src = ei;
    const int* dst = ei + E;

    char* base = (char*)d_ws;
    size_t off = 0;
    auto carve = [&](size_t bytes) {
        char* p = base + off;
        off = (off + bytes + 511) & ~(size_t)511;
        return p;
    };
    int*   cnt4    = (int*)carve((size_t)M * 4);
    int*   start4  = (int*)carve((size_t)(M + 1) * 4);
    int*   rank    = (int*)carve((size_t)E * 4);
    int*   elist   = (int*)carve((size_t)E * 4);
    int*   bsum    = (int*)carve(512 * 4);
    int*   boff    = (int*)carve(512 * 4);
    unsigned short* Wpack = (unsigned short*)carve((size_t)3 * 320 * 64 * 2);
    unsigned short* xb    = (unsigned short*)carve((size_t)N * 64 * 2);
    unsigned short* hb_a  = (unsigned short*)carve((size_t)N * 64 * 2);
    unsigned short* hb_b  = (unsigned short*)carve((size_t)N * 64 * 2);
    int*   gstart  = (int*)carve((size_t)(G + 1) * 4);
    (void)ws_size;

    hipMemsetAsync(cnt4, 0, (size_t)M * 4, stream);

    const int necnt = (E + 255) / 256;
    const int ncvt = (N * 64 / 4 + 255) / 256;
    const int nwp  = (3 * 320 * 64 + 255) / 256;
    const int ngb  = (N + 255) / 256;
    k_prep<<<necnt + ncvt + nwp + ngb, 256, 0, stream>>>(
        dst, et, cnt4, rank, E, necnt,
        x, xb, ncvt, W1, root1, Wl, rootl, Wpack, nwp,
        batch, gstart, N, G);

    int nb = (M + 1023) / 1024;
    k_scan1<<<nb, 256, 0, stream>>>(cnt4, start4, bsum, M);
    k_scan2<<<1, 512, 0, stream>>>(bsum, boff, nb);
    k_scan3<<<(M + 1 + 255) / 256, 256, 0, stream>>>(start4, boff, M, E);
    k_fill<<<(E + 255) / 256, 256, 0, stream>>>(src, dst, et, start4, rank, elist, E);

    const int cb = (N + TILE - 1) / TILE;
    const int WSTRIDE = 320 * 64;
    k_conv<<<cb, 256, 0, stream>>>(xb,   hb_a, elist, start4, Wpack,               b1,      N);
    k_conv<<<cb, 256, 0, stream>>>(hb_a, hb_b, elist, start4, Wpack + WSTRIDE,     bl,      N);
    k_conv<<<cb, 256, 0, stream>>>(hb_b, hb_a, elist, start4, Wpack + 2 * WSTRIDE, bl + 64, N);

    k_poolmlp<<<G, 256, 0, stream>>>(hb_a, gstart, l1w, l1b, l2w, l2b, out);
}